// Round 13
// baseline (81.856 us; speedup 1.0000x reference)
//
#include <hip/hip_runtime.h>
#include <math.h>

// Problem constants
#define T_STEPS 50
#define NS      2048
#define IND     16
#define HID     128
#define GATES   512
#define RR      8
#define KN      32
#define EPSV    1e-10f

// LSTM: 512 blocks x 4 real rows x 8 waves, TARGET 2 blocks/CU.
// Unified-register accounting (the r7/r8/r11 failure cause): r12 ran at
// 84 VGPR + 64 AGPR = 148 unified -> only 13 waves/CU fit -> no co-residency.
// This version: launch_bounds(512,4) (128 unified cap) + per-kf Ah loads
// + per-fragment keep-alive (compiler free to place Bh in AGPR) -> ~60v+64a.
#define LROWS   4
#define LTH     512
#define XPAD    20      // sX row stride (f16)

typedef _Float16 f16x8 __attribute__((ext_vector_type(8)));
typedef _Float16 f16x4 __attribute__((ext_vector_type(4)));
typedef float    f32x4 __attribute__((ext_vector_type(4)));

__device__ __forceinline__ float rcp_(float x)  { return __builtin_amdgcn_rcpf(x); }
__device__ __forceinline__ float sigm(float x)  { return rcp_(1.0f + __expf(-x)); }
__device__ __forceinline__ float tanhf_(float x){ return 1.0f - 2.0f * rcp_(1.0f + __expf(2.0f * x)); }

// ---------------------------------------------------------------------------
// LSTM via MFMA f16. 4 real rows at M-rows {0,4,8,12}: C-reg 0 of every lane
// is a real cell (1 cell/lane -> 10 TRANS/wave, no cross-lane ops).
// x via sX + 16x16x16 MFMA; h-only sA [2][16][128] XOR-swizzled; one barrier
// per step. Two independent blocks per CU drift and hide each other's
// barrier->ds_read->MFMA->TRANS latency chain.
// ---------------------------------------------------------------------------
__global__ __launch_bounds__(LTH, 4) void lstm_mfma_kernel(
    const float* __restrict__ x,     // (T, NS, IND)
    const float* __restrict__ W_ih,  // (GATES, IND)
    const float* __restrict__ W_hh,  // (GATES, HID)
    const float* __restrict__ b_ih,  // (GATES)
    const float* __restrict__ b_hh,  // (GATES)
    float* __restrict__ se,          // (NS, HID) out fp32
    _Float16* __restrict__ se16)     // (NS, HID) out f16
{
    __shared__ __align__(16) _Float16 sA[2][16][HID];          // 8 KB, swizzled
    __shared__ __align__(16) _Float16 sX[T_STEPS][16][XPAD];   // 31.25 KB

    const int tid    = threadIdx.x;
    const int w      = tid >> 6;       // wave 0..7
    const int l      = tid & 63;
    const int lane16 = l & 15;
    const int lgrp   = l >> 4;         // 0..3
    const int n0     = blockIdx.x * LROWS;

    // ---- prologue: W -> f16 fragments (static all 50 steps)
    // gate col gi = 128*gg + 16*w + lane16
    // Bx[gg]:     k = lgrp*4 + j         (x part, K=16)
    // Bh[gg][kf]: k = kf*32 + lgrp*8 + j (h part, K=128)
    f16x8 Bh[4][4];
    f16x4 Bx[4];
    float bias[4];
#pragma unroll
    for (int gg = 0; gg < 4; ++gg) {
        const int gi = 128 * gg + 16 * w + lane16;
        bias[gg] = b_ih[gi] + b_hh[gi];
        f16x4 vx;
#pragma unroll
        for (int j = 0; j < 4; ++j)
            vx[j] = (_Float16)W_ih[gi * IND + lgrp * 4 + j];
        Bx[gg] = vx;
        asm volatile("" : "+v"(Bx[gg]));          // keep-alive, low transit
#pragma unroll
        for (int kf = 0; kf < 4; ++kf) {
            f16x8 v;
            const float* p = W_hh + gi * HID + kf * 32 + lgrp * 8;
#pragma unroll
            for (int j = 0; j < 8; ++j) v[j] = (_Float16)p[j];
            Bh[gg][kf] = v;
            asm volatile("" : "+v"(Bh[gg][kf]));  // per-frag: compiler may park in AGPR
        }
    }

    // zero sA (h0=0; non-{0,4,8,12} M-rows stay zero) and sX (odd rows zero)
    for (int i = tid; i < 2 * 16 * HID; i += LTH)
        (&sA[0][0][0])[i] = (_Float16)0.0f;
    for (int i = tid; i < T_STEPS * 16 * XPAD; i += LTH)
        (&sX[0][0][0])[i] = (_Float16)0.0f;
    __syncthreads();

    // stage ALL x once: real row ri -> M-row 4*ri
    for (int i = tid; i < T_STEPS * LROWS * IND; i += LTH) {
        const int t = i >> 6, e = i & 63;
        sX[t][4 * (e >> 4)][e & 15] = (_Float16)x[((size_t)t * NS + n0) * IND + e];
    }
    __syncthreads();

    // lane owns ONE cell: real row lgrp (M-row 4*lgrp), col 16w+lane16
    const int axor  = (lane16 & 7) << 4;
    const int abase = lane16 * (HID * 2);
    const int hrow  = 4 * lgrp;
    const int hb    = hrow * (HID * 2) + ((((16 * w + lane16) * 2)) ^ ((hrow & 7) << 4));

    float c = 0.f, h = 0.f;

    for (int step = 0; step < T_STEPS; ++step) {
        const int cur = step & 1;
        const char* ab = (const char*)&sA[cur][0][0] + abase;

        f16x4 Ax = *(const f16x4*)&sX[step][lane16][lgrp * 4];

        f32x4 az0 = {bias[0], bias[0], bias[0], bias[0]};
        f32x4 az1 = {bias[1], bias[1], bias[1], bias[1]};
        f32x4 az2 = {bias[2], bias[2], bias[2], bias[2]};
        f32x4 az3 = {bias[3], bias[3], bias[3], bias[3]};
        az0 = __builtin_amdgcn_mfma_f32_16x16x16f16(Ax, Bx[0], az0, 0, 0, 0);
        az1 = __builtin_amdgcn_mfma_f32_16x16x16f16(Ax, Bx[1], az1, 0, 0, 0);
        az2 = __builtin_amdgcn_mfma_f32_16x16x16f16(Ax, Bx[2], az2, 0, 0, 0);
        az3 = __builtin_amdgcn_mfma_f32_16x16x16f16(Ax, Bx[3], az3, 0, 0, 0);
#pragma unroll
        for (int kf = 0; kf < 4; ++kf) {
            // per-kf A load: only ONE f16x8 live at a time (v-reg diet)
            f16x8 Ah = *(const f16x8*)(ab + ((kf * 64 + lgrp * 16) ^ axor));
            az0 = __builtin_amdgcn_mfma_f32_16x16x32_f16(Ah, Bh[0][kf], az0, 0, 0, 0);
            az1 = __builtin_amdgcn_mfma_f32_16x16x32_f16(Ah, Bh[1][kf], az1, 0, 0, 0);
            az2 = __builtin_amdgcn_mfma_f32_16x16x32_f16(Ah, Bh[2][kf], az2, 0, 0, 0);
            az3 = __builtin_amdgcn_mfma_f32_16x16x32_f16(Ah, Bh[3][kf], az3, 0, 0, 0);
        }

        // cell update on C-reg 0 only
        c = sigm(az1[0]) * c + sigm(az0[0]) * tanhf_(az2[0]);
        h = sigm(az3[0]) * tanhf_(c);

        if (step + 1 < T_STEPS) {
            char* wb = (char*)&sA[cur ^ 1][0][0];
            *(_Float16*)(wb + hb) = (_Float16)h;
        }
        __syncthreads();
    }

    se[(n0 + lgrp) * HID + 16 * w + lane16]   = h;
    se16[(n0 + lgrp) * HID + 16 * w + lane16] = (_Float16)h;
}

// ---------------------------------------------------------------------------
// Kernel 2: precompute sw[n] = se[n].w_att[0:H] and p2[n] = se[n].w_att[H:2H].
// ---------------------------------------------------------------------------
__global__ __launch_bounds__(256) void precompute_kernel(
    const float* __restrict__ se,     // (NS, HID)
    const float* __restrict__ w_att,  // (2H + R)
    float* __restrict__ sw,           // (NS)
    float* __restrict__ p2n)          // (NS)
{
    const int wid  = threadIdx.x >> 6;
    const int lane = threadIdx.x & 63;
    const int n    = blockIdx.x * 4 + wid;

    const float a = se[n * HID + lane];
    const float b = se[n * HID + 64 + lane];
    float d1 = a * w_att[lane]       + b * w_att[64 + lane];
    float d2 = a * w_att[HID + lane] + b * w_att[HID + 64 + lane];
#pragma unroll
    for (int d = 32; d > 0; d >>= 1) {
        d1 += __shfl_xor(d1, d);
        d2 += __shfl_xor(d2, d);
    }
    if (lane == 0) { sw[n] = d1; p2n[n] = d2; }
}

// ---------------------------------------------------------------------------
// Kernel 3: FUSED attention + combine (round-10 proven).
// ---------------------------------------------------------------------------
__global__ __launch_bounds__(512) void attn_fused_kernel(
    const _Float16* __restrict__ se16,   // (NS, HID) f16
    const float* __restrict__ se,        // (NS, HID) fp32 (residual)
    const int*   __restrict__ neighbors, // (RR, NS, KN)
    const float* __restrict__ rel_num,   // (RR, NS)
    const float* __restrict__ sw,        // (NS)
    const float* __restrict__ p2n,       // (NS)
    const float* __restrict__ w_att,     // (2H + R)
    const float* __restrict__ b_att,     // (1)
    const float* __restrict__ w_rel,     // (H + R)
    const float* __restrict__ b_rel,     // (1)
    const float* __restrict__ w_fc1,     // (HID)
    const float* __restrict__ b_fc1,     // (1)
    float* __restrict__ out)             // (NS)
{
    __shared__ float srel[RR][HID];      // 4 KB
    __shared__ float srsc[RR];

    const int r    = threadIdx.x >> 6;   // wave = relation 0..7
    const int lane = threadIdx.x & 63;
    const int n    = blockIdx.x;
    const size_t pair = (size_t)r * NS + n;
    const f16x4* se16_4 = (const f16x4*)se16;

    int myidx = 0;
    if (lane < KN) myidx = neighbors[pair * KN + lane];

    // ---- score: one scalar gather per neighbor (zero row -> dot = 0)
    float s = 0.f;
    if (lane < KN) {
        float swv = (myidx != 0) ? sw[myidx - 1] : 0.f;
        s = swv + p2n[n] + w_att[2 * HID + r] + b_att[0];
    }
    float mx = s;
#pragma unroll
    for (int d = 16; d > 0; d >>= 1) mx = fmaxf(mx, __shfl_xor(mx, d, 32));
    float e  = __expf(s - mx);
    float sm = e;
#pragma unroll
    for (int d = 16; d > 0; d >>= 1) sm += __shfl_xor(sm, d, 32);
    float att = e * rcp_(sm);    // valid in lanes 0..31

    // ---- weighted sum: lanes as (k2 = lane>>5, c4 = lane&31)
    const int k2 = lane >> 5;
    const int c4 = lane & 31;
    float ax = 0.f, ay = 0.f, az = 0.f, aw = 0.f;
#pragma unroll
    for (int kk = 0; kk < KN / 2; ++kk) {
        const int   kq = kk * 2 + k2;
        const float av = __shfl(att, kq);
        const int  idq = __shfl(myidx, kq);
        if (idq != 0) {
            f16x4 v = se16_4[(size_t)(idq - 1) * (HID / 4) + c4];
            ax += av * (float)v[0]; ay += av * (float)v[1];
            az += av * (float)v[2]; aw += av * (float)v[3];
        }
    }
    ax += __shfl_xor(ax, 32); ay += __shfl_xor(ay, 32);
    az += __shfl_xor(az, 32); aw += __shfl_xor(aw, 32);

    const float inv = rcp_(rel_num[pair] + EPSV);
    float pr = 0.f;
    if (k2 == 0) {
        ax *= inv; ay *= inv; az *= inv; aw *= inv;
        *(float4*)&srel[r][c4 * 4] = make_float4(ax, ay, az, aw);
        pr = ax * w_rel[c4 * 4] + ay * w_rel[c4 * 4 + 1]
           + az * w_rel[c4 * 4 + 2] + aw * w_rel[c4 * 4 + 3];
    }
#pragma unroll
    for (int d = 16; d > 0; d >>= 1) pr += __shfl_xor(pr, d, 32);
    if (lane == 0) srsc[r] = pr + w_rel[HID + r] + b_rel[0];

    __syncthreads();   // the only block-wide barrier

    if (r == 0) {
        float rs[RR];
        float rmx = -1e30f;
#pragma unroll
        for (int q = 0; q < RR; ++q) {
            rs[q] = srsc[q];
            rmx = fmaxf(rmx, rs[q]);
        }
        float rsm = 0.f;
#pragma unroll
        for (int q = 0; q < RR; ++q) {
            rs[q] = __expf(rs[q] - rmx);
            rsm += rs[q];
        }
        const float invs = rcp_(rsm * (float)RR);

        float u0 = 0.f, u1 = 0.f;
#pragma unroll
        for (int q = 0; q < RR; ++q) {
            u0 += rs[q] * srel[q][lane];
            u1 += rs[q] * srel[q][64 + lane];
        }
        u0 = u0 * invs + se[n * HID + lane];
        u1 = u1 * invs + se[n * HID + 64 + lane];

        float p = u0 * w_fc1[lane] + u1 * w_fc1[64 + lane];
#pragma unroll
        for (int d = 32; d > 0; d >>= 1) p += __shfl_xor(p, d);
        if (lane == 0) out[n] = p + b_fc1[0];
    }
}

// ---------------------------------------------------------------------------
extern "C" void kernel_launch(void* const* d_in, const int* in_sizes, int n_in,
                              void* d_out, int out_size, void* d_ws, size_t ws_size,
                              hipStream_t stream) {
    const float* x      = (const float*)d_in[0];
    const int*   nbrs   = (const int*)  d_in[1];
    const float* relnum = (const float*)d_in[2];
    const float* W_ih   = (const float*)d_in[3];
    const float* W_hh   = (const float*)d_in[4];
    const float* b_ih   = (const float*)d_in[5];
    const float* b_hh   = (const float*)d_in[6];
    const float* w_att  = (const float*)d_in[7];
    const float* b_att  = (const float*)d_in[8];
    const float* w_rel  = (const float*)d_in[9];
    const float* b_rel  = (const float*)d_in[10];
    const float* w_fc1  = (const float*)d_in[11];
    const float* b_fc1  = (const float*)d_in[12];
    float* out = (float*)d_out;

    // workspace: se fp32 (1MB) | se16 f16 (512KB) | sw (8KB) | p2 (8KB)
    float*    se   = (float*)d_ws;
    _Float16* se16 = (_Float16*)(se + (size_t)NS * HID);
    float*    sw   = (float*)(se16 + (size_t)NS * HID);
    float*    p2n  = sw + NS;

    hipLaunchKernelGGL(lstm_mfma_kernel, dim3(NS / LROWS), dim3(LTH), 0, stream,
                       x, W_ih, W_hh, b_ih, b_hh, se, se16);
    hipLaunchKernelGGL(precompute_kernel, dim3(NS / 4), dim3(256), 0, stream,
                       se, w_att, sw, p2n);
    hipLaunchKernelGGL(attn_fused_kernel, dim3(NS), dim3(512), 0, stream,
                       se16, se, nbrs, relnum, sw, p2n, w_att, b_att,
                       w_rel, b_rel, w_fc1, b_fc1, out);
}

// Round 15
// 62.945 us; speedup vs baseline: 1.3004x; 1.3004x over previous
//
#include <hip/hip_runtime.h>
#include <math.h>

// Problem constants
#define T_STEPS 50
#define NS      2048
#define IND     16
#define HID     128
#define GATES   512
#define RR      8
#define KN      32
#define EPSV    1e-10f

// LSTM MFMA tiling (round-12 proven, best known-good): 256 blocks x 8 real
// rows at even M-rows, 8 waves, one barrier/step, VGPR 84, no spill.
#define LROWS   8
#define LTH     512
#define XPAD    20      // sX row stride (f16)

typedef _Float16 f16x8 __attribute__((ext_vector_type(8)));
typedef _Float16 f16x4 __attribute__((ext_vector_type(4)));
typedef float    f32x4 __attribute__((ext_vector_type(4)));

__device__ __forceinline__ float rcp_(float x)  { return __builtin_amdgcn_rcpf(x); }
__device__ __forceinline__ float sigm(float x)  { return rcp_(1.0f + __expf(-x)); }
__device__ __forceinline__ float tanhf_(float x){ return 1.0f - 2.0f * rcp_(1.0f + __expf(2.0f * x)); }

// ---------------------------------------------------------------------------
// LSTM via MFMA f16 (round-12 exact) + FUSED precompute epilogue.
// - 8 real rows at EVEN M-rows {0,2,...,14}: C-regs 0 and 2 of every lane
//   are real cells (2 cells/lane, zero cross-lane ops in the loop).
// - x staged once in sX (odd M-rows zero), consumed via 16x16x16 MFMA.
// - h-only sA [2][16][128], XOR-swizzled (byte ^= (row&7)<<4).
// - Weights register-resident (keep-alive asm); one barrier per step.
// - NEW: epilogue computes sw[n] = se[n].w_att[0:H] and p2n[n] =
//   se[n].w_att[H:2H] from the register-resident h (width-16 shuffle reduce
//   + 512B LDS cross-wave exchange) -> precompute kernel deleted.
// ---------------------------------------------------------------------------
__global__ __launch_bounds__(LTH, 2) void lstm_mfma_kernel(
    const float* __restrict__ x,     // (T, NS, IND)
    const float* __restrict__ W_ih,  // (GATES, IND)
    const float* __restrict__ W_hh,  // (GATES, HID)
    const float* __restrict__ b_ih,  // (GATES)
    const float* __restrict__ b_hh,  // (GATES)
    const float* __restrict__ w_att, // (2H + R)
    float* __restrict__ se,          // (NS, HID) out fp32
    _Float16* __restrict__ se16,     // (NS, HID) out f16
    float* __restrict__ sw,          // (NS) out: se.w_att[0:H]
    float* __restrict__ p2n)         // (NS) out: se.w_att[H:2H]
{
    __shared__ __align__(16) _Float16 sA[2][16][HID];          // 8 KB, swizzled
    __shared__ __align__(16) _Float16 sX[T_STEPS][16][XPAD];   // 31.25 KB
    __shared__ float spart[8][4][4];                           // 512 B

    const int tid    = threadIdx.x;
    const int w      = tid >> 6;       // wave 0..7
    const int l      = tid & 63;
    const int lane16 = l & 15;
    const int lgrp   = l >> 4;         // 0..3
    const int n0     = blockIdx.x * LROWS;

    // ---- prologue: W -> f16 fragments (static all 50 steps)
    // gate col gi = 128*gg + 16*w + lane16
    // Bx[gg]:     k = lgrp*4 + j         (x part, K=16)
    // Bh[gg][kf]: k = kf*32 + lgrp*8 + j (h part, K=128)
    f16x8 Bh[4][4];
    f16x4 Bx[4];
    float bias[4];
#pragma unroll
    for (int gg = 0; gg < 4; ++gg) {
        const int gi = 128 * gg + 16 * w + lane16;
        bias[gg] = b_ih[gi] + b_hh[gi];
        f16x4 vx;
#pragma unroll
        for (int j = 0; j < 4; ++j)
            vx[j] = (_Float16)W_ih[gi * IND + lgrp * 4 + j];
        Bx[gg] = vx;
#pragma unroll
        for (int kf = 0; kf < 4; ++kf) {
            f16x8 v;
            const float* p = W_hh + gi * HID + kf * 32 + lgrp * 8;
#pragma unroll
            for (int j = 0; j < 8; ++j) v[j] = (_Float16)p[j];
            Bh[gg][kf] = v;
        }
    }
    // Keep-alive: B cannot be rematerialized -> stays resident (r12 recipe).
#pragma unroll
    for (int gg = 0; gg < 4; ++gg) {
        asm volatile("" : "+v"(Bx[gg]));
#pragma unroll
        for (int kf = 0; kf < 4; ++kf)
            asm volatile("" : "+v"(Bh[gg][kf]));
    }

    // zero sA (h0=0; odd M-rows stay zero) and sX (odd M-rows zero)
    for (int i = tid; i < 2 * 16 * HID; i += LTH)
        (&sA[0][0][0])[i] = (_Float16)0.0f;
    for (int i = tid; i < T_STEPS * 16 * XPAD; i += LTH)
        (&sX[0][0][0])[i] = (_Float16)0.0f;
    __syncthreads();

    // stage ALL x once: real row ri -> M-row 2*ri (coalesced)
    for (int i = tid; i < T_STEPS * LROWS * IND; i += LTH) {
        const int t = i >> 7, e = i & 127;
        sX[t][2 * (e >> 4)][e & 15] = (_Float16)x[((size_t)t * NS + n0) * IND + e];
    }
    __syncthreads();

    // lane owns real rows 2*lgrp (C-reg 0) and 2*lgrp+1 (C-reg 2), col 16w+lane16
    const int axor  = (lane16 & 7) << 4;
    const int abase = lane16 * (HID * 2);
    const int hrow0 = 4 * lgrp, hrow1 = 4 * lgrp + 2;     // even M-rows
    const int hcol2 = (16 * w + lane16) * 2;
    const int hb0   = hrow0 * (HID * 2) + (hcol2 ^ ((hrow0 & 7) << 4));
    const int hb1   = hrow1 * (HID * 2) + (hcol2 ^ ((hrow1 & 7) << 4));

    float c0 = 0.f, c1 = 0.f, h0 = 0.f, h1 = 0.f;

    for (int step = 0; step < T_STEPS; ++step) {
        const int cur = step & 1;
        const char* ab = (const char*)&sA[cur][0][0] + abase;

        f16x4 Ax = *(const f16x4*)&sX[step][lane16][lgrp * 4];

        f16x8 Ah[4];
#pragma unroll
        for (int kf = 0; kf < 4; ++kf)
            Ah[kf] = *(const f16x8*)(ab + ((kf * 64 + lgrp * 16) ^ axor));

        f32x4 az0 = {bias[0], bias[0], bias[0], bias[0]};
        f32x4 az1 = {bias[1], bias[1], bias[1], bias[1]};
        f32x4 az2 = {bias[2], bias[2], bias[2], bias[2]};
        f32x4 az3 = {bias[3], bias[3], bias[3], bias[3]};
        az0 = __builtin_amdgcn_mfma_f32_16x16x16f16(Ax, Bx[0], az0, 0, 0, 0);
        az1 = __builtin_amdgcn_mfma_f32_16x16x16f16(Ax, Bx[1], az1, 0, 0, 0);
        az2 = __builtin_amdgcn_mfma_f32_16x16x16f16(Ax, Bx[2], az2, 0, 0, 0);
        az3 = __builtin_amdgcn_mfma_f32_16x16x16f16(Ax, Bx[3], az3, 0, 0, 0);
#pragma unroll
        for (int kf = 0; kf < 4; ++kf) {
            az0 = __builtin_amdgcn_mfma_f32_16x16x32_f16(Ah[kf], Bh[0][kf], az0, 0, 0, 0);
            az1 = __builtin_amdgcn_mfma_f32_16x16x32_f16(Ah[kf], Bh[1][kf], az1, 0, 0, 0);
            az2 = __builtin_amdgcn_mfma_f32_16x16x32_f16(Ah[kf], Bh[2][kf], az2, 0, 0, 0);
            az3 = __builtin_amdgcn_mfma_f32_16x16x32_f16(Ah[kf], Bh[3][kf], az3, 0, 0, 0);
        }

        // cell update on C-regs 0 and 2 (both real; no cross-lane ops)
        c0 = sigm(az1[0]) * c0 + sigm(az0[0]) * tanhf_(az2[0]);
        h0 = sigm(az3[0]) * tanhf_(c0);
        c1 = sigm(az1[2]) * c1 + sigm(az0[2]) * tanhf_(az2[2]);
        h1 = sigm(az3[2]) * tanhf_(c1);

        // write h_{t+1} (swizzled) into the other buffer; one barrier per step
        if (step + 1 < T_STEPS) {
            char* wb = (char*)&sA[cur ^ 1][0][0];
            *(_Float16*)(wb + hb0) = (_Float16)h0;
            *(_Float16*)(wb + hb1) = (_Float16)h1;
        }
        __syncthreads();
    }

    // ---- se / se16 stores
    const int col = 16 * w + lane16;
    se[(n0 + 2 * lgrp) * HID + col]       = h0;
    se[(n0 + 2 * lgrp + 1) * HID + col]   = h1;
    se16[(n0 + 2 * lgrp) * HID + col]     = (_Float16)h0;
    se16[(n0 + 2 * lgrp + 1) * HID + col] = (_Float16)h1;

    // ---- FUSED precompute epilogue: sw / p2n for this block's 8 rows.
    // partials: j0 = h0.w_nb, j1 = h1.w_nb, j2 = h0.w_self, j3 = h1.w_self
    float d0 = h0 * w_att[col];
    float d1 = h1 * w_att[col];
    float d2 = h0 * w_att[HID + col];
    float d3 = h1 * w_att[HID + col];
    // reduce over the 16 lanes of this lane16-group (cols 16w..16w+15)
#pragma unroll
    for (int m = 8; m > 0; m >>= 1) {
        d0 += __shfl_xor(d0, m);
        d1 += __shfl_xor(d1, m);
        d2 += __shfl_xor(d2, m);
        d3 += __shfl_xor(d3, m);
    }
    if (lane16 == 0) {
        spart[w][lgrp][0] = d0;
        spart[w][lgrp][1] = d1;
        spart[w][lgrp][2] = d2;
        spart[w][lgrp][3] = d3;
    }
    __syncthreads();
    // 16 threads finish: local row r8 = 2*lg + o ; q selects sw vs p2n
    if (tid < 16) {
        const int r8 = tid >> 1;          // 0..7
        const int q  = tid & 1;           // 0 -> sw, 1 -> p2n
        const int lg = r8 >> 1, o = r8 & 1;
        float v = 0.f;
#pragma unroll
        for (int ww = 0; ww < 8; ++ww)
            v += spart[ww][lg][o + 2 * q];
        if (q == 0) sw[n0 + r8] = v;
        else        p2n[n0 + r8] = v;
    }
}

// ---------------------------------------------------------------------------
// Kernel 2: FUSED attention + combine (round-10 proven, unchanged).
// ---------------------------------------------------------------------------
__global__ __launch_bounds__(512) void attn_fused_kernel(
    const _Float16* __restrict__ se16,   // (NS, HID) f16
    const float* __restrict__ se,        // (NS, HID) fp32 (residual)
    const int*   __restrict__ neighbors, // (RR, NS, KN)
    const float* __restrict__ rel_num,   // (RR, NS)
    const float* __restrict__ sw,        // (NS)
    const float* __restrict__ p2n,       // (NS)
    const float* __restrict__ w_att,     // (2H + R)
    const float* __restrict__ b_att,     // (1)
    const float* __restrict__ w_rel,     // (H + R)
    const float* __restrict__ b_rel,     // (1)
    const float* __restrict__ w_fc1,     // (HID)
    const float* __restrict__ b_fc1,     // (1)
    float* __restrict__ out)             // (NS)
{
    __shared__ float srel[RR][HID];      // 4 KB
    __shared__ float srsc[RR];

    const int r    = threadIdx.x >> 6;   // wave = relation 0..7
    const int lane = threadIdx.x & 63;
    const int n    = blockIdx.x;
    const size_t pair = (size_t)r * NS + n;
    const f16x4* se16_4 = (const f16x4*)se16;

    int myidx = 0;
    if (lane < KN) myidx = neighbors[pair * KN + lane];

    // ---- score: one scalar gather per neighbor (zero row -> dot = 0)
    float s = 0.f;
    if (lane < KN) {
        float swv = (myidx != 0) ? sw[myidx - 1] : 0.f;
        s = swv + p2n[n] + w_att[2 * HID + r] + b_att[0];
    }
    float mx = s;
#pragma unroll
    for (int d = 16; d > 0; d >>= 1) mx = fmaxf(mx, __shfl_xor(mx, d, 32));
    float e  = __expf(s - mx);
    float sm = e;
#pragma unroll
    for (int d = 16; d > 0; d >>= 1) sm += __shfl_xor(sm, d, 32);
    float att = e * rcp_(sm);    // valid in lanes 0..31

    // ---- weighted sum: lanes as (k2 = lane>>5, c4 = lane&31)
    const int k2 = lane >> 5;
    const int c4 = lane & 31;
    float ax = 0.f, ay = 0.f, az = 0.f, aw = 0.f;
#pragma unroll
    for (int kk = 0; kk < KN / 2; ++kk) {
        const int   kq = kk * 2 + k2;
        const float av = __shfl(att, kq);
        const int  idq = __shfl(myidx, kq);
        if (idq != 0) {
            f16x4 v = se16_4[(size_t)(idq - 1) * (HID / 4) + c4];
            ax += av * (float)v[0]; ay += av * (float)v[1];
            az += av * (float)v[2]; aw += av * (float)v[3];
        }
    }
    ax += __shfl_xor(ax, 32); ay += __shfl_xor(ay, 32);
    az += __shfl_xor(az, 32); aw += __shfl_xor(aw, 32);

    const float inv = rcp_(rel_num[pair] + EPSV);
    float pr = 0.f;
    if (k2 == 0) {
        ax *= inv; ay *= inv; az *= inv; aw *= inv;
        *(float4*)&srel[r][c4 * 4] = make_float4(ax, ay, az, aw);
        pr = ax * w_rel[c4 * 4] + ay * w_rel[c4 * 4 + 1]
           + az * w_rel[c4 * 4 + 2] + aw * w_rel[c4 * 4 + 3];
    }
#pragma unroll
    for (int d = 16; d > 0; d >>= 1) pr += __shfl_xor(pr, d, 32);
    if (lane == 0) srsc[r] = pr + w_rel[HID + r] + b_rel[0];

    __syncthreads();   // the only block-wide barrier

    if (r == 0) {
        float rs[RR];
        float rmx = -1e30f;
#pragma unroll
        for (int q = 0; q < RR; ++q) {
            rs[q] = srsc[q];
            rmx = fmaxf(rmx, rs[q]);
        }
        float rsm = 0.f;
#pragma unroll
        for (int q = 0; q < RR; ++q) {
            rs[q] = __expf(rs[q] - rmx);
            rsm += rs[q];
        }
        const float invs = rcp_(rsm * (float)RR);

        float u0 = 0.f, u1 = 0.f;
#pragma unroll
        for (int q = 0; q < RR; ++q) {
            u0 += rs[q] * srel[q][lane];
            u1 += rs[q] * srel[q][64 + lane];
        }
        u0 = u0 * invs + se[n * HID + lane];
        u1 = u1 * invs + se[n * HID + 64 + lane];

        float p = u0 * w_fc1[lane] + u1 * w_fc1[64 + lane];
#pragma unroll
        for (int d = 32; d > 0; d >>= 1) p += __shfl_xor(p, d);
        if (lane == 0) out[n] = p + b_fc1[0];
    }
}

// ---------------------------------------------------------------------------
extern "C" void kernel_launch(void* const* d_in, const int* in_sizes, int n_in,
                              void* d_out, int out_size, void* d_ws, size_t ws_size,
                              hipStream_t stream) {
    const float* x      = (const float*)d_in[0];
    const int*   nbrs   = (const int*)  d_in[1];
    const float* relnum = (const float*)d_in[2];
    const float* W_ih   = (const float*)d_in[3];
    const float* W_hh   = (const float*)d_in[4];
    const float* b_ih   = (const float*)d_in[5];
    const float* b_hh   = (const float*)d_in[6];
    const float* w_att  = (const float*)d_in[7];
    const float* b_att  = (const float*)d_in[8];
    const float* w_rel  = (const float*)d_in[9];
    const float* b_rel  = (const float*)d_in[10];
    const float* w_fc1  = (const float*)d_in[11];
    const float* b_fc1  = (const float*)d_in[12];
    float* out = (float*)d_out;

    // workspace: se fp32 (1MB) | se16 f16 (512KB) | sw (8KB) | p2 (8KB)
    float*    se   = (float*)d_ws;
    _Float16* se16 = (_Float16*)(se + (size_t)NS * HID);
    float*    sw   = (float*)(se16 + (size_t)NS * HID);
    float*    p2n  = sw + NS;

    hipLaunchKernelGGL(lstm_mfma_kernel, dim3(NS / LROWS), dim3(LTH), 0, stream,
                       x, W_ih, W_hh, b_ih, b_hh, w_att, se, se16, sw, p2n);
    hipLaunchKernelGGL(attn_fused_kernel, dim3(NS), dim3(512), 0, stream,
                       se16, se, nbrs, relnum, sw, p2n, w_att, b_att,
                       w_rel, b_rel, w_fc1, b_fc1, out);
}

// Round 16
// 59.231 us; speedup vs baseline: 1.3820x; 1.0627x over previous
//
#include <hip/hip_runtime.h>
#include <math.h>

// Problem constants
#define T_STEPS 50
#define NS      2048
#define IND     16
#define HID     128
#define GATES   512
#define RR      8
#define KN      32
#define EPSV    1e-10f

// LSTM MFMA tiling (round-12/15 proven): 256 blocks x 8 real rows at even
// M-rows, 8 waves, one barrier/step, no spill.
#define LROWS   8
#define LTH     512
#define XPAD    20      // sX row stride (f16)

#define LOG2E      1.44269504f
#define TWO_LOG2E  2.88539008f

typedef _Float16 f16x8 __attribute__((ext_vector_type(8)));
typedef _Float16 f16x4 __attribute__((ext_vector_type(4)));
typedef float    f32x4 __attribute__((ext_vector_type(4)));

__device__ __forceinline__ float rcp_(float x)  { return __builtin_amdgcn_rcpf(x); }
// exp2-domain activations: z~ already carries the log2e scale (folded into W/bias)
__device__ __forceinline__ float sigm2(float zt) {           // zt = -log2e * z
    return rcp_(1.0f + __builtin_amdgcn_exp2f(zt));
}
__device__ __forceinline__ float tanh2(float zt) {           // zt = 2*log2e * z
    return 1.0f - 2.0f * rcp_(1.0f + __builtin_amdgcn_exp2f(zt));
}
// plain-domain helpers for attn/combine
__device__ __forceinline__ float sigm(float x)  { return rcp_(1.0f + __expf(-x)); }

// ---------------------------------------------------------------------------
// LSTM via MFMA f16 (round-15 structure + critical-path edits):
// - 8 real rows at EVEN M-rows; C-regs 0,2 real; 2 cells/lane.
// - x-part (sX read + 4 x-MFMAs) software-pipelined ACROSS the barrier:
//   az-init for step t+1 is computed pre-barrier (depends only on read-only
//   sX), so the post-barrier path is Ah-reads -> h-MFMAs -> TRANS only.
// - per-gate log2e prescaling of W/bias: activations use raw v_exp_f32.
// - h0 written to LDS before c1/h1 are computed (earlier lgkm drain).
// - Fused sw/p2n epilogue (r15).
// ---------------------------------------------------------------------------
__global__ __launch_bounds__(LTH, 2) void lstm_mfma_kernel(
    const float* __restrict__ x,     // (T, NS, IND)
    const float* __restrict__ W_ih,  // (GATES, IND)
    const float* __restrict__ W_hh,  // (GATES, HID)
    const float* __restrict__ b_ih,  // (GATES)
    const float* __restrict__ b_hh,  // (GATES)
    const float* __restrict__ w_att, // (2H + R)
    float* __restrict__ se,          // (NS, HID) out fp32
    _Float16* __restrict__ se16,     // (NS, HID) out f16
    float* __restrict__ sw,          // (NS) out: se.w_att[0:H]
    float* __restrict__ p2n)         // (NS) out: se.w_att[H:2H]
{
    __shared__ __align__(16) _Float16 sA[2][16][HID];          // 8 KB, swizzled
    __shared__ __align__(16) _Float16 sX[T_STEPS][16][XPAD];   // 31.25 KB
    __shared__ float spart[8][4][4];                           // 512 B

    const int tid    = threadIdx.x;
    const int w      = tid >> 6;       // wave 0..7
    const int l      = tid & 63;
    const int lane16 = l & 15;
    const int lgrp   = l >> 4;         // 0..3
    const int n0     = blockIdx.x * LROWS;

    // ---- prologue: W -> f16 fragments, PRESCALED per gate group.
    // gates i(0), f(1), o(3): scale -log2e  (sigm2 domain)
    // gate  g(2):             scale +2log2e (tanh2 domain)
    f16x8 Bh[4][4];
    f16x4 Bx[4];
    float bias[4];
#pragma unroll
    for (int gg = 0; gg < 4; ++gg) {
        const float sc = (gg == 2) ? TWO_LOG2E : -LOG2E;
        const int gi = 128 * gg + 16 * w + lane16;
        bias[gg] = sc * (b_ih[gi] + b_hh[gi]);
        f16x4 vx;
#pragma unroll
        for (int j = 0; j < 4; ++j)
            vx[j] = (_Float16)(sc * W_ih[gi * IND + lgrp * 4 + j]);
        Bx[gg] = vx;
#pragma unroll
        for (int kf = 0; kf < 4; ++kf) {
            f16x8 v;
            const float* p = W_hh + gi * HID + kf * 32 + lgrp * 8;
#pragma unroll
            for (int j = 0; j < 8; ++j) v[j] = (_Float16)(sc * p[j]);
            Bh[gg][kf] = v;
        }
    }
    // Keep-alive: B cannot be rematerialized -> stays resident (r12 recipe).
#pragma unroll
    for (int gg = 0; gg < 4; ++gg) {
        asm volatile("" : "+v"(Bx[gg]));
#pragma unroll
        for (int kf = 0; kf < 4; ++kf)
            asm volatile("" : "+v"(Bh[gg][kf]));
    }

    // zero sA (h0=0; odd M-rows stay zero) and sX (odd M-rows zero)
    for (int i = tid; i < 2 * 16 * HID; i += LTH)
        (&sA[0][0][0])[i] = (_Float16)0.0f;
    for (int i = tid; i < T_STEPS * 16 * XPAD; i += LTH)
        (&sX[0][0][0])[i] = (_Float16)0.0f;
    __syncthreads();

    // stage ALL x once: real row ri -> M-row 2*ri (coalesced)
    for (int i = tid; i < T_STEPS * LROWS * IND; i += LTH) {
        const int t = i >> 7, e = i & 127;
        sX[t][2 * (e >> 4)][e & 15] = (_Float16)x[((size_t)t * NS + n0) * IND + e];
    }
    __syncthreads();

    // lane owns real rows 2*lgrp (C-reg 0) and 2*lgrp+1 (C-reg 2), col 16w+lane16
    const int axor  = (lane16 & 7) << 4;
    const int abase = lane16 * (HID * 2);
    const int hrow0 = 4 * lgrp, hrow1 = 4 * lgrp + 2;     // even M-rows
    const int hcol2 = (16 * w + lane16) * 2;
    const int hb0   = hrow0 * (HID * 2) + (hcol2 ^ ((hrow0 & 7) << 4));
    const int hb1   = hrow1 * (HID * 2) + (hcol2 ^ ((hrow1 & 7) << 4));

    float c0 = 0.f, c1 = 0.f, h0 = 0.f, h1 = 0.f;

    // pipelined x-part accumulators for the CURRENT step (step 0 here)
    f32x4 azx0, azx1, azx2, azx3;
    {
        f16x4 Ax = *(const f16x4*)&sX[0][lane16][lgrp * 4];
        azx0 = (f32x4){bias[0], bias[0], bias[0], bias[0]};
        azx1 = (f32x4){bias[1], bias[1], bias[1], bias[1]};
        azx2 = (f32x4){bias[2], bias[2], bias[2], bias[2]};
        azx3 = (f32x4){bias[3], bias[3], bias[3], bias[3]};
        azx0 = __builtin_amdgcn_mfma_f32_16x16x16f16(Ax, Bx[0], azx0, 0, 0, 0);
        azx1 = __builtin_amdgcn_mfma_f32_16x16x16f16(Ax, Bx[1], azx1, 0, 0, 0);
        azx2 = __builtin_amdgcn_mfma_f32_16x16x16f16(Ax, Bx[2], azx2, 0, 0, 0);
        azx3 = __builtin_amdgcn_mfma_f32_16x16x16f16(Ax, Bx[3], azx3, 0, 0, 0);
    }

    for (int step = 0; step < T_STEPS; ++step) {
        const int cur = step & 1;
        const char* ab = (const char*)&sA[cur][0][0] + abase;

        // post-barrier critical path: Ah reads -> h-MFMAs (az seeded by azx)
        f16x8 Ah[4];
#pragma unroll
        for (int kf = 0; kf < 4; ++kf)
            Ah[kf] = *(const f16x8*)(ab + ((kf * 64 + lgrp * 16) ^ axor));

        f32x4 az0 = azx0, az1 = azx1, az2 = azx2, az3 = azx3;
#pragma unroll
        for (int kf = 0; kf < 4; ++kf) {
            az0 = __builtin_amdgcn_mfma_f32_16x16x32_f16(Ah[kf], Bh[0][kf], az0, 0, 0, 0);
            az1 = __builtin_amdgcn_mfma_f32_16x16x32_f16(Ah[kf], Bh[1][kf], az1, 0, 0, 0);
            az2 = __builtin_amdgcn_mfma_f32_16x16x32_f16(Ah[kf], Bh[2][kf], az2, 0, 0, 0);
            az3 = __builtin_amdgcn_mfma_f32_16x16x32_f16(Ah[kf], Bh[3][kf], az3, 0, 0, 0);
        }

        // pre-compute az-init for step+1 (reads only sX -> overlaps TRANS below)
        if (step + 1 < T_STEPS) {
            f16x4 Ax = *(const f16x4*)&sX[step + 1][lane16][lgrp * 4];
            azx0 = (f32x4){bias[0], bias[0], bias[0], bias[0]};
            azx1 = (f32x4){bias[1], bias[1], bias[1], bias[1]};
            azx2 = (f32x4){bias[2], bias[2], bias[2], bias[2]};
            azx3 = (f32x4){bias[3], bias[3], bias[3], bias[3]};
            azx0 = __builtin_amdgcn_mfma_f32_16x16x16f16(Ax, Bx[0], azx0, 0, 0, 0);
            azx1 = __builtin_amdgcn_mfma_f32_16x16x16f16(Ax, Bx[1], azx1, 0, 0, 0);
            azx2 = __builtin_amdgcn_mfma_f32_16x16x16f16(Ax, Bx[2], azx2, 0, 0, 0);
            azx3 = __builtin_amdgcn_mfma_f32_16x16x16f16(Ax, Bx[3], azx3, 0, 0, 0);
        }

        char* wb = (char*)&sA[cur ^ 1][0][0];

        // cell 0: compute and write EARLY (starts lgkm drain sooner)
        c0 = sigm2(az1[0]) * c0 + sigm2(az0[0]) * tanh2(az2[0]);
        h0 = sigm2(az3[0]) * tanh2(TWO_LOG2E * c0);
        if (step + 1 < T_STEPS)
            *(_Float16*)(wb + hb0) = (_Float16)h0;

        // cell 1
        c1 = sigm2(az1[2]) * c1 + sigm2(az0[2]) * tanh2(az2[2]);
        h1 = sigm2(az3[2]) * tanh2(TWO_LOG2E * c1);
        if (step + 1 < T_STEPS)
            *(_Float16*)(wb + hb1) = (_Float16)h1;

        __syncthreads();
    }

    // ---- se / se16 stores
    const int col = 16 * w + lane16;
    se[(n0 + 2 * lgrp) * HID + col]       = h0;
    se[(n0 + 2 * lgrp + 1) * HID + col]   = h1;
    se16[(n0 + 2 * lgrp) * HID + col]     = (_Float16)h0;
    se16[(n0 + 2 * lgrp + 1) * HID + col] = (_Float16)h1;

    // ---- FUSED precompute epilogue (r15): sw / p2n for this block's 8 rows.
    float d0 = h0 * w_att[col];
    float d1 = h1 * w_att[col];
    float d2 = h0 * w_att[HID + col];
    float d3 = h1 * w_att[HID + col];
#pragma unroll
    for (int m = 8; m > 0; m >>= 1) {
        d0 += __shfl_xor(d0, m);
        d1 += __shfl_xor(d1, m);
        d2 += __shfl_xor(d2, m);
        d3 += __shfl_xor(d3, m);
    }
    if (lane16 == 0) {
        spart[w][lgrp][0] = d0;
        spart[w][lgrp][1] = d1;
        spart[w][lgrp][2] = d2;
        spart[w][lgrp][3] = d3;
    }
    __syncthreads();
    if (tid < 16) {
        const int r8 = tid >> 1;          // 0..7
        const int q  = tid & 1;           // 0 -> sw, 1 -> p2n
        const int lg = r8 >> 1, o = r8 & 1;
        float v = 0.f;
#pragma unroll
        for (int ww = 0; ww < 8; ++ww)
            v += spart[ww][lg][o + 2 * q];
        if (q == 0) sw[n0 + r8] = v;
        else        p2n[n0 + r8] = v;
    }
}

// ---------------------------------------------------------------------------
// Kernel 2: FUSED attention + combine (round-10 proven, unchanged).
// ---------------------------------------------------------------------------
__global__ __launch_bounds__(512) void attn_fused_kernel(
    const _Float16* __restrict__ se16,   // (NS, HID) f16
    const float* __restrict__ se,        // (NS, HID) fp32 (residual)
    const int*   __restrict__ neighbors, // (RR, NS, KN)
    const float* __restrict__ rel_num,   // (RR, NS)
    const float* __restrict__ sw,        // (NS)
    const float* __restrict__ p2n,       // (NS)
    const float* __restrict__ w_att,     // (2H + R)
    const float* __restrict__ b_att,     // (1)
    const float* __restrict__ w_rel,     // (H + R)
    const float* __restrict__ b_rel,     // (1)
    const float* __restrict__ w_fc1,     // (HID)
    const float* __restrict__ b_fc1,     // (1)
    float* __restrict__ out)             // (NS)
{
    __shared__ float srel[RR][HID];      // 4 KB
    __shared__ float srsc[RR];

    const int r    = threadIdx.x >> 6;   // wave = relation 0..7
    const int lane = threadIdx.x & 63;
    const int n    = blockIdx.x;
    const size_t pair = (size_t)r * NS + n;
    const f16x4* se16_4 = (const f16x4*)se16;

    int myidx = 0;
    if (lane < KN) myidx = neighbors[pair * KN + lane];

    // ---- score: one scalar gather per neighbor (zero row -> dot = 0)
    float s = 0.f;
    if (lane < KN) {
        float swv = (myidx != 0) ? sw[myidx - 1] : 0.f;
        s = swv + p2n[n] + w_att[2 * HID + r] + b_att[0];
    }
    float mx = s;
#pragma unroll
    for (int d = 16; d > 0; d >>= 1) mx = fmaxf(mx, __shfl_xor(mx, d, 32));
    float e  = __expf(s - mx);
    float sm = e;
#pragma unroll
    for (int d = 16; d > 0; d >>= 1) sm += __shfl_xor(sm, d, 32);
    float att = e * rcp_(sm);    // valid in lanes 0..31

    // ---- weighted sum: lanes as (k2 = lane>>5, c4 = lane&31)
    const int k2 = lane >> 5;
    const int c4 = lane & 31;
    float ax = 0.f, ay = 0.f, az = 0.f, aw = 0.f;
#pragma unroll
    for (int kk = 0; kk < KN / 2; ++kk) {
        const int   kq = kk * 2 + k2;
        const float av = __shfl(att, kq);
        const int  idq = __shfl(myidx, kq);
        if (idq != 0) {
            f16x4 v = se16_4[(size_t)(idq - 1) * (HID / 4) + c4];
            ax += av * (float)v[0]; ay += av * (float)v[1];
            az += av * (float)v[2]; aw += av * (float)v[3];
        }
    }
    ax += __shfl_xor(ax, 32); ay += __shfl_xor(ay, 32);
    az += __shfl_xor(az, 32); aw += __shfl_xor(aw, 32);

    const float inv = rcp_(rel_num[pair] + EPSV);
    float pr = 0.f;
    if (k2 == 0) {
        ax *= inv; ay *= inv; az *= inv; aw *= inv;
        *(float4*)&srel[r][c4 * 4] = make_float4(ax, ay, az, aw);
        pr = ax * w_rel[c4 * 4] + ay * w_rel[c4 * 4 + 1]
           + az * w_rel[c4 * 4 + 2] + aw * w_rel[c4 * 4 + 3];
    }
#pragma unroll
    for (int d = 16; d > 0; d >>= 1) pr += __shfl_xor(pr, d, 32);
    if (lane == 0) srsc[r] = pr + w_rel[HID + r] + b_rel[0];

    __syncthreads();   // the only block-wide barrier

    if (r == 0) {
        float rs[RR];
        float rmx = -1e30f;
#pragma unroll
        for (int q = 0; q < RR; ++q) {
            rs[q] = srsc[q];
            rmx = fmaxf(rmx, rs[q]);
        }
        float rsm = 0.f;
#pragma unroll
        for (int q = 0; q < RR; ++q) {
            rs[q] = __expf(rs[q] - rmx);
            rsm += rs[q];
        }
        const float invs = rcp_(rsm * (float)RR);

        float u0 = 0.f, u1 = 0.f;
#pragma unroll
        for (int q = 0; q < RR; ++q) {
            u0 += rs[q] * srel[q][lane];
            u1 += rs[q] * srel[q][64 + lane];
        }
        u0 = u0 * invs + se[n * HID + lane];
        u1 = u1 * invs + se[n * HID + 64 + lane];

        float p = u0 * w_fc1[lane] + u1 * w_fc1[64 + lane];
#pragma unroll
        for (int d = 32; d > 0; d >>= 1) p += __shfl_xor(p, d);
        if (lane == 0) out[n] = p + b_fc1[0];
    }
}

// ---------------------------------------------------------------------------
extern "C" void kernel_launch(void* const* d_in, const int* in_sizes, int n_in,
                              void* d_out, int out_size, void* d_ws, size_t ws_size,
                              hipStream_t stream) {
    const float* x      = (const float*)d_in[0];
    const int*   nbrs   = (const int*)  d_in[1];
    const float* relnum = (const float*)d_in[2];
    const float* W_ih   = (const float*)d_in[3];
    const float* W_hh   = (const float*)d_in[4];
    const float* b_ih   = (const float*)d_in[5];
    const float* b_hh   = (const float*)d_in[6];
    const float* w_att  = (const float*)d_in[7];
    const float* b_att  = (const float*)d_in[8];
    const float* w_rel  = (const float*)d_in[9];
    const float* b_rel  = (const float*)d_in[10];
    const float* w_fc1  = (const float*)d_in[11];
    const float* b_fc1  = (const float*)d_in[12];
    float* out = (float*)d_out;

    // workspace: se fp32 (1MB) | se16 f16 (512KB) | sw (8KB) | p2 (8KB)
    float*    se   = (float*)d_ws;
    _Float16* se16 = (_Float16*)(se + (size_t)NS * HID);
    float*    sw   = (float*)(se16 + (size_t)NS * HID);
    float*    p2n  = sw + NS;

    hipLaunchKernelGGL(lstm_mfma_kernel, dim3(NS / LROWS), dim3(LTH), 0, stream,
                       x, W_ih, W_hh, b_ih, b_hh, w_att, se, se16, sw, p2n);
    hipLaunchKernelGGL(attn_fused_kernel, dim3(NS), dim3(512), 0, stream,
                       se16, se, nbrs, relnum, sw, p2n, w_att, b_att,
                       w_rel, b_rel, w_fc1, b_fc1, out);
}

// Round 17
// 57.466 us; speedup vs baseline: 1.4244x; 1.0307x over previous
//
#include <hip/hip_runtime.h>
#include <math.h>

// Problem constants
#define T_STEPS 50
#define NS      2048
#define IND     16
#define HID     128
#define GATES   512
#define RR      8
#define KN      32
#define EPSV    1e-10f

// LSTM MFMA tiling (round-12/15/16 proven): 256 blocks x 8 real rows at even
// M-rows, 8 waves, one barrier/step, no spill.
#define LROWS   8
#define LTH     512
#define XPAD    20      // sX row stride (f16)

#define LOG2E      1.44269504f
#define TWO_LOG2E  2.88539008f

typedef _Float16 f16x8 __attribute__((ext_vector_type(8)));
typedef _Float16 f16x4 __attribute__((ext_vector_type(4)));
typedef float    f32x4 __attribute__((ext_vector_type(4)));

__device__ __forceinline__ float rcp_(float x)  { return __builtin_amdgcn_rcpf(x); }
// exp2-domain activations: z~ already carries the log2e scale (folded into W/bias)
__device__ __forceinline__ float sigm2(float zt) {           // zt = -log2e * z
    return rcp_(1.0f + __builtin_amdgcn_exp2f(zt));
}
__device__ __forceinline__ float tanh2(float zt) {           // zt = 2*log2e * z
    return 1.0f - 2.0f * rcp_(1.0f + __builtin_amdgcn_exp2f(zt));
}

// ---------------------------------------------------------------------------
// LSTM via MFMA f16 (round-16 proven, byte-identical):
// - 8 real rows at EVEN M-rows; C-regs 0,2 real; 2 cells/lane.
// - x-part software-pipelined across the barrier (azx carried).
// - per-gate log2e prescaling of W/bias: raw v_exp_f32 activations.
// - h0 written to LDS before c1/h1 (earlier lgkm drain).
// - Fused sw/p2n epilogue.
// ---------------------------------------------------------------------------
__global__ __launch_bounds__(LTH, 2) void lstm_mfma_kernel(
    const float* __restrict__ x,     // (T, NS, IND)
    const float* __restrict__ W_ih,  // (GATES, IND)
    const float* __restrict__ W_hh,  // (GATES, HID)
    const float* __restrict__ b_ih,  // (GATES)
    const float* __restrict__ b_hh,  // (GATES)
    const float* __restrict__ w_att, // (2H + R)
    float* __restrict__ se,          // (NS, HID) out fp32
    _Float16* __restrict__ se16,     // (NS, HID) out f16
    float* __restrict__ sw,          // (NS) out: se.w_att[0:H]
    float* __restrict__ p2n)         // (NS) out: se.w_att[H:2H]
{
    __shared__ __align__(16) _Float16 sA[2][16][HID];          // 8 KB, swizzled
    __shared__ __align__(16) _Float16 sX[T_STEPS][16][XPAD];   // 31.25 KB
    __shared__ float spart[8][4][4];                           // 512 B

    const int tid    = threadIdx.x;
    const int w      = tid >> 6;       // wave 0..7
    const int l      = tid & 63;
    const int lane16 = l & 15;
    const int lgrp   = l >> 4;         // 0..3
    const int n0     = blockIdx.x * LROWS;

    // ---- prologue: W -> f16 fragments, PRESCALED per gate group.
    f16x8 Bh[4][4];
    f16x4 Bx[4];
    float bias[4];
#pragma unroll
    for (int gg = 0; gg < 4; ++gg) {
        const float sc = (gg == 2) ? TWO_LOG2E : -LOG2E;
        const int gi = 128 * gg + 16 * w + lane16;
        bias[gg] = sc * (b_ih[gi] + b_hh[gi]);
        f16x4 vx;
#pragma unroll
        for (int j = 0; j < 4; ++j)
            vx[j] = (_Float16)(sc * W_ih[gi * IND + lgrp * 4 + j]);
        Bx[gg] = vx;
#pragma unroll
        for (int kf = 0; kf < 4; ++kf) {
            f16x8 v;
            const float* p = W_hh + gi * HID + kf * 32 + lgrp * 8;
#pragma unroll
            for (int j = 0; j < 8; ++j) v[j] = (_Float16)(sc * p[j]);
            Bh[gg][kf] = v;
        }
    }
#pragma unroll
    for (int gg = 0; gg < 4; ++gg) {
        asm volatile("" : "+v"(Bx[gg]));
#pragma unroll
        for (int kf = 0; kf < 4; ++kf)
            asm volatile("" : "+v"(Bh[gg][kf]));
    }

    for (int i = tid; i < 2 * 16 * HID; i += LTH)
        (&sA[0][0][0])[i] = (_Float16)0.0f;
    for (int i = tid; i < T_STEPS * 16 * XPAD; i += LTH)
        (&sX[0][0][0])[i] = (_Float16)0.0f;
    __syncthreads();

    for (int i = tid; i < T_STEPS * LROWS * IND; i += LTH) {
        const int t = i >> 7, e = i & 127;
        sX[t][2 * (e >> 4)][e & 15] = (_Float16)x[((size_t)t * NS + n0) * IND + e];
    }
    __syncthreads();

    const int axor  = (lane16 & 7) << 4;
    const int abase = lane16 * (HID * 2);
    const int hrow0 = 4 * lgrp, hrow1 = 4 * lgrp + 2;     // even M-rows
    const int hcol2 = (16 * w + lane16) * 2;
    const int hb0   = hrow0 * (HID * 2) + (hcol2 ^ ((hrow0 & 7) << 4));
    const int hb1   = hrow1 * (HID * 2) + (hcol2 ^ ((hrow1 & 7) << 4));

    float c0 = 0.f, c1 = 0.f, h0 = 0.f, h1 = 0.f;

    f32x4 azx0, azx1, azx2, azx3;
    {
        f16x4 Ax = *(const f16x4*)&sX[0][lane16][lgrp * 4];
        azx0 = (f32x4){bias[0], bias[0], bias[0], bias[0]};
        azx1 = (f32x4){bias[1], bias[1], bias[1], bias[1]};
        azx2 = (f32x4){bias[2], bias[2], bias[2], bias[2]};
        azx3 = (f32x4){bias[3], bias[3], bias[3], bias[3]};
        azx0 = __builtin_amdgcn_mfma_f32_16x16x16f16(Ax, Bx[0], azx0, 0, 0, 0);
        azx1 = __builtin_amdgcn_mfma_f32_16x16x16f16(Ax, Bx[1], azx1, 0, 0, 0);
        azx2 = __builtin_amdgcn_mfma_f32_16x16x16f16(Ax, Bx[2], azx2, 0, 0, 0);
        azx3 = __builtin_amdgcn_mfma_f32_16x16x16f16(Ax, Bx[3], azx3, 0, 0, 0);
    }

    for (int step = 0; step < T_STEPS; ++step) {
        const int cur = step & 1;
        const char* ab = (const char*)&sA[cur][0][0] + abase;

        f16x8 Ah[4];
#pragma unroll
        for (int kf = 0; kf < 4; ++kf)
            Ah[kf] = *(const f16x8*)(ab + ((kf * 64 + lgrp * 16) ^ axor));

        f32x4 az0 = azx0, az1 = azx1, az2 = azx2, az3 = azx3;
#pragma unroll
        for (int kf = 0; kf < 4; ++kf) {
            az0 = __builtin_amdgcn_mfma_f32_16x16x32_f16(Ah[kf], Bh[0][kf], az0, 0, 0, 0);
            az1 = __builtin_amdgcn_mfma_f32_16x16x32_f16(Ah[kf], Bh[1][kf], az1, 0, 0, 0);
            az2 = __builtin_amdgcn_mfma_f32_16x16x32_f16(Ah[kf], Bh[2][kf], az2, 0, 0, 0);
            az3 = __builtin_amdgcn_mfma_f32_16x16x32_f16(Ah[kf], Bh[3][kf], az3, 0, 0, 0);
        }

        if (step + 1 < T_STEPS) {
            f16x4 Ax = *(const f16x4*)&sX[step + 1][lane16][lgrp * 4];
            azx0 = (f32x4){bias[0], bias[0], bias[0], bias[0]};
            azx1 = (f32x4){bias[1], bias[1], bias[1], bias[1]};
            azx2 = (f32x4){bias[2], bias[2], bias[2], bias[2]};
            azx3 = (f32x4){bias[3], bias[3], bias[3], bias[3]};
            azx0 = __builtin_amdgcn_mfma_f32_16x16x16f16(Ax, Bx[0], azx0, 0, 0, 0);
            azx1 = __builtin_amdgcn_mfma_f32_16x16x16f16(Ax, Bx[1], azx1, 0, 0, 0);
            azx2 = __builtin_amdgcn_mfma_f32_16x16x16f16(Ax, Bx[2], azx2, 0, 0, 0);
            azx3 = __builtin_amdgcn_mfma_f32_16x16x16f16(Ax, Bx[3], azx3, 0, 0, 0);
        }

        char* wb = (char*)&sA[cur ^ 1][0][0];

        c0 = sigm2(az1[0]) * c0 + sigm2(az0[0]) * tanh2(az2[0]);
        h0 = sigm2(az3[0]) * tanh2(TWO_LOG2E * c0);
        if (step + 1 < T_STEPS)
            *(_Float16*)(wb + hb0) = (_Float16)h0;

        c1 = sigm2(az1[2]) * c1 + sigm2(az0[2]) * tanh2(az2[2]);
        h1 = sigm2(az3[2]) * tanh2(TWO_LOG2E * c1);
        if (step + 1 < T_STEPS)
            *(_Float16*)(wb + hb1) = (_Float16)h1;

        __syncthreads();
    }

    const int col = 16 * w + lane16;
    se[(n0 + 2 * lgrp) * HID + col]       = h0;
    se[(n0 + 2 * lgrp + 1) * HID + col]   = h1;
    se16[(n0 + 2 * lgrp) * HID + col]     = (_Float16)h0;
    se16[(n0 + 2 * lgrp + 1) * HID + col] = (_Float16)h1;

    float d0 = h0 * w_att[col];
    float d1 = h1 * w_att[col];
    float d2 = h0 * w_att[HID + col];
    float d3 = h1 * w_att[HID + col];
#pragma unroll
    for (int m = 8; m > 0; m >>= 1) {
        d0 += __shfl_xor(d0, m);
        d1 += __shfl_xor(d1, m);
        d2 += __shfl_xor(d2, m);
        d3 += __shfl_xor(d3, m);
    }
    if (lane16 == 0) {
        spart[w][lgrp][0] = d0;
        spart[w][lgrp][1] = d1;
        spart[w][lgrp][2] = d2;
        spart[w][lgrp][3] = d3;
    }
    __syncthreads();
    if (tid < 16) {
        const int r8 = tid >> 1;          // 0..7
        const int q  = tid & 1;           // 0 -> sw, 1 -> p2n
        const int lg = r8 >> 1, o = r8 & 1;
        float v = 0.f;
#pragma unroll
        for (int ww = 0; ww < 8; ++ww)
            v += spart[ww][lg][o + 2 * q];
        if (q == 0) sw[n0 + r8] = v;
        else        p2n[n0 + r8] = v;
    }
}

// ---------------------------------------------------------------------------
// Kernel 2: FUSED attention + combine. Weighted-sum restructured for MLP:
// lane = (q = lane>>4 row-slot, c8 = lane&15 chunk); each iter reads 4 full
// se16 rows via f16x8 (16B/lane) -> 8 iters instead of 16, half the loads
// and shfl pairs, 2x bytes in flight. Cross-q reduce via 2 shfl_xor per acc.
// ---------------------------------------------------------------------------
__global__ __launch_bounds__(512) void attn_fused_kernel(
    const _Float16* __restrict__ se16,   // (NS, HID) f16
    const float* __restrict__ se,        // (NS, HID) fp32 (residual)
    const int*   __restrict__ neighbors, // (RR, NS, KN)
    const float* __restrict__ rel_num,   // (RR, NS)
    const float* __restrict__ sw,        // (NS)
    const float* __restrict__ p2n,       // (NS)
    const float* __restrict__ w_att,     // (2H + R)
    const float* __restrict__ b_att,     // (1)
    const float* __restrict__ w_rel,     // (H + R)
    const float* __restrict__ b_rel,     // (1)
    const float* __restrict__ w_fc1,     // (HID)
    const float* __restrict__ b_fc1,     // (1)
    float* __restrict__ out)             // (NS)
{
    __shared__ float srel[RR][HID];      // 4 KB
    __shared__ float srsc[RR];

    const int r    = threadIdx.x >> 6;   // wave = relation 0..7
    const int lane = threadIdx.x & 63;
    const int n    = blockIdx.x;
    const size_t pair = (size_t)r * NS + n;

    int myidx = 0;
    if (lane < KN) myidx = neighbors[pair * KN + lane];

    // ---- score: one scalar gather per neighbor (zero row -> dot = 0)
    float s = 0.f;
    if (lane < KN) {
        float swv = (myidx != 0) ? sw[myidx - 1] : 0.f;
        s = swv + p2n[n] + w_att[2 * HID + r] + b_att[0];
    }
    float mx = s;
#pragma unroll
    for (int d = 16; d > 0; d >>= 1) mx = fmaxf(mx, __shfl_xor(mx, d, 32));
    float e  = __expf(s - mx);
    float sm = e;
#pragma unroll
    for (int d = 16; d > 0; d >>= 1) sm += __shfl_xor(sm, d, 32);
    float att = e * rcp_(sm);    // valid in lanes 0..31

    // ---- weighted sum: q = lane>>4 (row-slot 0..3), c8 = lane&15 (16B chunk)
    // iter kk reads 4 full f16 rows (k = kk*4 + q), coalesced per 16 lanes.
    const int q  = lane >> 4;
    const int c8 = lane & 15;
    const f16x8* se16_8 = (const f16x8*)se16;   // row stride = HID/8 = 16
    float acc[8];
#pragma unroll
    for (int j = 0; j < 8; ++j) acc[j] = 0.f;
#pragma unroll
    for (int kk = 0; kk < KN / 4; ++kk) {       // 8 iters
        const int   kq = kk * 4 + q;
        const float av = __shfl(att, kq);
        const int  idq = __shfl(myidx, kq);
        if (idq != 0) {
            f16x8 v = se16_8[(size_t)(idq - 1) * 16 + c8];
#pragma unroll
            for (int j = 0; j < 8; ++j) acc[j] += av * (float)v[j];
        }
    }
    // reduce across the 4 row-slots (lanes lane, lane^16, lane^32, lane^48)
#pragma unroll
    for (int j = 0; j < 8; ++j) {
        acc[j] += __shfl_xor(acc[j], 16);
        acc[j] += __shfl_xor(acc[j], 32);
    }

    const float inv = rcp_(rel_num[pair] + EPSV);
    float pr = 0.f;
    if (q == 0) {   // lanes 0..15 hold final sums for cols c8*8 .. c8*8+7
#pragma unroll
        for (int j = 0; j < 8; ++j) acc[j] *= inv;
        float4 w0 = make_float4(acc[0], acc[1], acc[2], acc[3]);
        float4 w1 = make_float4(acc[4], acc[5], acc[6], acc[7]);
        *(float4*)&srel[r][c8 * 8]     = w0;
        *(float4*)&srel[r][c8 * 8 + 4] = w1;
#pragma unroll
        for (int j = 0; j < 8; ++j) pr += acc[j] * w_rel[c8 * 8 + j];
    }
#pragma unroll
    for (int d = 8; d > 0; d >>= 1) pr += __shfl_xor(pr, d, 16);
    if (lane == 0) srsc[r] = pr + w_rel[HID + r] + b_rel[0];

    __syncthreads();   // the only block-wide barrier

    if (r == 0) {
        float rs[RR];
        float rmx = -1e30f;
#pragma unroll
        for (int qq = 0; qq < RR; ++qq) {
            rs[qq] = srsc[qq];
            rmx = fmaxf(rmx, rs[qq]);
        }
        float rsm = 0.f;
#pragma unroll
        for (int qq = 0; qq < RR; ++qq) {
            rs[qq] = __expf(rs[qq] - rmx);
            rsm += rs[qq];
        }
        const float invs = rcp_(rsm * (float)RR);

        float u0 = 0.f, u1 = 0.f;
#pragma unroll
        for (int qq = 0; qq < RR; ++qq) {
            u0 += rs[qq] * srel[qq][lane];
            u1 += rs[qq] * srel[qq][64 + lane];
        }
        u0 = u0 * invs + se[n * HID + lane];
        u1 = u1 * invs + se[n * HID + 64 + lane];

        float p = u0 * w_fc1[lane] + u1 * w_fc1[64 + lane];
#pragma unroll
        for (int d = 32; d > 0; d >>= 1) p += __shfl_xor(p, d);
        if (lane == 0) out[n] = p + b_fc1[0];
    }
}

// ---------------------------------------------------------------------------
extern "C" void kernel_launch(void* const* d_in, const int* in_sizes, int n_in,
                              void* d_out, int out_size, void* d_ws, size_t ws_size,
                              hipStream_t stream) {
    const float* x      = (const float*)d_in[0];
    const int*   nbrs   = (const int*)  d_in[1];
    const float* relnum = (const float*)d_in[2];
    const float* W_ih   = (const float*)d_in[3];
    const float* W_hh   = (const float*)d_in[4];
    const float* b_ih   = (const float*)d_in[5];
    const float* b_hh   = (const float*)d_in[6];
    const float* w_att  = (const float*)d_in[7];
    const float* b_att  = (const float*)d_in[8];
    const float* w_rel  = (const float*)d_in[9];
    const float* b_rel  = (const float*)d_in[10];
    const float* w_fc1  = (const float*)d_in[11];
    const float* b_fc1  = (const float*)d_in[12];
    float* out = (float*)d_out;

    // workspace: se fp32 (1MB) | se16 f16 (512KB) | sw (8KB) | p2 (8KB)
    float*    se   = (float*)d_ws;
    _Float16* se16 = (_Float16*)(se + (size_t)NS * HID);
    float*    sw   = (float*)(se16 + (size_t)NS * HID);
    float*    p2n  = sw + NS;

    hipLaunchKernelGGL(lstm_mfma_kernel, dim3(NS / LROWS), dim3(LTH), 0, stream,
                       x, W_ih, W_hh, b_ih, b_hh, w_att, se, se16, sw, p2n);
    hipLaunchKernelGGL(attn_fused_kernel, dim3(NS), dim3(512), 0, stream,
                       se16, se, nbrs, relnum, sw, p2n, w_att, b_att,
                       w_rel, b_rel, w_fc1, b_fc1, out);
}